// Round 6
// baseline (283.210 us; speedup 1.0000x reference)
//
#include <hip/hip_runtime.h>
#include <math.h>

#define IMG_H 3072
#define IMG_W 4096
#define Hh 1536
#define Wh 2048
#define S (Hh*Wh)   // 3,145,728 per-plane pixels

#define TID 32   // rows/thread, fused denoise (trip = TID+8 = 40, unroll 5 = ring period)
#define TVL 8    // rows/thread, LTM vertical sliding pass (8 -> 2x blocks, latency-bound fix)
#define HBLK 192 // output cols per block in LTM horizontal / fused vh pass (4 waves x 48)

#if __has_builtin(__builtin_amdgcn_rcpf)
#define RCP(x) __builtin_amdgcn_rcpf(x)
#else
#define RCP(x) (1.0f/(x))
#endif

__device__ __forceinline__ float clamp01(float v){ return fminf(fmaxf(v, 0.0f), 1.0f); }

// jnp.interp over knots (0,0),(0.25,0.5),(1,1) then black-level
__device__ __forceinline__ float decompand_black(float v){
  float y = (v <= 0.25f) ? (2.0f*v) : fmaf(v - 0.25f, 0.5f/0.75f, 0.5f);
  y = clamp01(y);
  return clamp01((y - 0.0625f) * (1.0f/0.9375f));
}

// x^(1/2.2): v_log_f32 + v_exp_f32 (__builtin_amdgcn_logf IS log2)
__device__ __forceinline__ float gamma22(float x){
  return __builtin_amdgcn_exp2f(0.45454545454545453f * __builtin_amdgcn_logf(x));
}

// ---- K1: decompand + split into 4 RGGB planes (2 quarter-cols/thread) + zero sums ----
__global__ __launch_bounds__(256) void k_split(const float* __restrict__ x, float* __restrict__ P,
                                               float* __restrict__ sums){
  int idx = blockIdx.x*256 + threadIdx.x;
  int i = idx >> 10, jq = (idx & 1023)*2;
  const float* r0 = x + (size_t)(2*i)*IMG_W + 2*jq;
  float4 a = *(const float4*)r0;
  float4 b = *(const float4*)(r0 + IMG_W);
  size_t o = (size_t)i*Wh + jq;
  *(float2*)(P + o)            = make_float2(decompand_black(a.x), decompand_black(a.z));
  *(float2*)(P + S + o)        = make_float2(decompand_black(a.y), decompand_black(a.w));
  *(float2*)(P + 2*(size_t)S + o) = make_float2(decompand_black(b.x), decompand_black(b.z));
  *(float2*)(P + 3*(size_t)S + o) = make_float2(decompand_black(b.y), decompand_black(b.w));
  if (blockIdx.x == 0 && threadIdx.x < 4) sums[threadIdx.x] = 0.f;
}

// ---- fused guided-filter denoise (r=2, eps=100), 2 output columns/thread ----
// a-cols k=0..5 <-> col c0-2+k ; I-cols c0-4..c0+5 (10). FAST: interior, count=25.
template<int TI, bool FAST>
__device__ __forceinline__ void denoise_col2(const float* __restrict__ in, float* __restrict__ D,
                                             int c0, int i0, float& local){
  const float inv25 = 1.0f/25.0f;
  float cw_a[6], amask[6], cw_o0 = 25.f, cw_o1 = 25.f;
  if (!FAST){
    #pragma unroll
    for (int k=0;k<6;++k){
      int pc = c0 + k - 2;
      bool ok = ((unsigned)pc < (unsigned)Wh);
      amask[k] = ok ? 1.f : 0.f;
      cw_a[k]  = ok ? (float)(min(pc+2, Wh-1) - max(pc-2, 0) + 1) : 1.f;
    }
    cw_o0 = (float)(min(c0+2, Wh-1)   - max(c0-2, 0) + 1);
    cw_o1 = (float)(min(c0+3, Wh-1)   - max(c0-1, 0) + 1);
  }

  float rh1[6][5]={{0}}, rh2[6][5]={{0}};
  float vs1[6]={0}, vs2[6]={0};
  float rha0[5]={0}, rhb0[5]={0}, rha1[5]={0}, rhb1[5]={0};
  float cI0[5]={0}, cI1[5]={0};
  float wa0=0.f, wb0=0.f, wa1=0.f, wb1=0.f;

  const float* rp = in + (size_t)(i0-4)*Wh + c0;   // loads rp[-4..5]
  float* wp = D + (size_t)i0*Wh + c0;

  #pragma unroll 5
  for (int rr=0; rr<TI+8; ++rr){
    int r = i0 - 4 + rr;
    float v[10];
    if (FAST){
      float2 p0 = *(const float2*)(rp-4);
      float2 p1 = *(const float2*)(rp-2);
      float2 p2 = *(const float2*)(rp);
      float2 p3 = *(const float2*)(rp+2);
      float2 p4 = *(const float2*)(rp+4);
      v[0]=p0.x; v[1]=p0.y; v[2]=p1.x; v[3]=p1.y; v[4]=p2.x;
      v[5]=p2.y; v[6]=p3.x; v[7]=p3.y; v[8]=p4.x; v[9]=p4.y;
    } else {
      if ((unsigned)r < (unsigned)Hh){
        #pragma unroll
        for (int d=0; d<10; ++d){
          int c = c0 + d - 4;
          v[d] = ((unsigned)c < (unsigned)Wh) ? rp[d-4] : 0.f;
        }
      } else {
        #pragma unroll
        for (int d=0; d<10; ++d) v[d]=0.f;
      }
    }
    rp += Wh;
    float sq[10];
    #pragma unroll
    for (int d=0; d<10; ++d) sq[d]=v[d]*v[d];
    float h1[6], h2[6];
    h1[0]=v[0]+v[1]+v[2]+v[3]+v[4];
    h2[0]=sq[0]+sq[1]+sq[2]+sq[3]+sq[4];
    #pragma unroll
    for (int k=1;k<6;++k){
      h1[k]=h1[k-1]-v[k-1]+v[k+4];
      h2[k]=h2[k-1]-sq[k-1]+sq[k+4];
    }
    #pragma unroll
    for (int k=0;k<6;++k){
      vs1[k]+=h1[k]-rh1[k][0];
      vs2[k]+=h2[k]-rh2[k][0];
      #pragma unroll
      for (int t=0;t<4;++t){ rh1[k][t]=rh1[k][t+1]; rh2[k][t]=rh2[k][t+1]; }
      rh1[k][4]=h1[k]; rh2[k][4]=h2[k];
    }
    #pragma unroll
    for (int t=0;t<4;++t){ cI0[t]=cI0[t+1]; cI1[t]=cI1[t+1]; }
    cI0[4]=v[4]; cI1[4]=v[5];

    if (rr >= 4){
      int q = r-2;
      float a6[6], b6[6];
      if (FAST){
        #pragma unroll
        for (int k=0;k<6;++k){
          float m   = vs1[k]*inv25;
          float var = fmaf(-m, m, vs2[k]*inv25);
          float a   = var*RCP(var + 100.0f);
          a6[k] = a; b6[k] = fmaf(-m, a, m);
        }
      } else {
        float rmask = ((unsigned)q < (unsigned)Hh) ? 1.f : 0.f;
        float rh = (float)(min(q+2, Hh-1) - max(q-2, 0) + 1);
        #pragma unroll
        for (int k=0;k<6;++k){
          float inv = RCP(rh*cw_a[k]);
          float m   = vs1[k]*inv;
          float var = fmaf(-m, m, vs2[k]*inv);
          float a   = var*RCP(var + 100.0f);
          float b   = fmaf(-m, a, m);
          a6[k] = a*amask[k]*rmask; b6[k] = b*amask[k]*rmask;
        }
      }
      float ha0 = a6[0]+a6[1]+a6[2]+a6[3]+a6[4];
      float hb0 = b6[0]+b6[1]+b6[2]+b6[3]+b6[4];
      float ha1 = ha0 - a6[0] + a6[5];
      float hb1 = hb0 - b6[0] + b6[5];
      wa0 += ha0 - rha0[0]; wb0 += hb0 - rhb0[0];
      wa1 += ha1 - rha1[0]; wb1 += hb1 - rhb1[0];
      #pragma unroll
      for (int t=0;t<4;++t){
        rha0[t]=rha0[t+1]; rhb0[t]=rhb0[t+1];
        rha1[t]=rha1[t+1]; rhb1[t]=rhb1[t+1];
      }
      rha0[4]=ha0; rhb0[4]=hb0; rha1[4]=ha1; rhb1[4]=hb1;

      if (rr >= 8){
        int ro = r-4;
        float invo0, invo1;
        if (FAST){ invo0 = inv25; invo1 = inv25; }
        else {
          float rho = (float)(min(ro+2, Hh-1) - max(ro-2, 0) + 1);
          invo0 = RCP(rho*cw_o0); invo1 = RCP(rho*cw_o1);
        }
        float d0 = fmaf(wa0*invo0, cI0[0], wb0*invo0);
        float d1 = fmaf(wa1*invo1, cI1[0], wb1*invo1);
        *(float2*)wp = make_float2(d0, d1); wp += Wh;
        local += d0 + d1;
      }
    }
  }
}

template<int TI>
__global__ __launch_bounds__(256) void k_denoise(const float* __restrict__ P4,
                                                 float* __restrict__ D4,
                                                 float* __restrict__ sums){
  const int c0 = (blockIdx.x*256 + threadIdx.x)*2;
  const int i0 = blockIdx.y*TI;
  const int pl = blockIdx.z;
  const float* __restrict__ in = P4 + (size_t)pl*S;
  float* __restrict__ D = D4 + (size_t)pl*S;
  float local = 0.f;

  // wave-uniform fast check: wave covers cols [cmin, cmin+127], touches [cmin-4, cmin+131]
  const int cmin = (blockIdx.x*256 + (threadIdx.x & ~63))*2;
  const bool rows_ok = (i0 >= 4) && (i0 + TI + 4 <= Hh);
  const bool fast = rows_ok && (cmin >= 4) && (cmin + 131 < Wh);
  if (fast) denoise_col2<TI, true >(in, D, c0, i0, local);
  else      denoise_col2<TI, false>(in, D, c0, i0, local);

  __shared__ float red[256];
  red[threadIdx.x]=local;
  __syncthreads();
  #pragma unroll
  for (int off=128; off>0; off>>=1){
    if (threadIdx.x<off) red[threadIdx.x]+=red[threadIdx.x+off];
    __syncthreads();
  }
  if (threadIdx.x==0) atomicAdd(sums+pl, red[0]);
}

// ==================== LTM guided filter (r=8), separable sliding/prefix ====================
// Horizontal 17-tap window sums via per-wave inclusive prefix sum.
// Each wave: loads 64 cols [ob-8, ob+55], produces 48 outputs [ob, ob+47].
// Window sum for output o (lane o<48): P[o+16] - P[o-1], edge cols contribute 0 (truncated).
// SQUARE=true: in2 := in1^2 (first pass: sums of Ys and Ys^2).
template<bool SQUARE>
__global__ __launch_bounds__(256) void k_ltm_h(const float* __restrict__ X1,
                                               const float* __restrict__ X2,
                                               float* __restrict__ O1,
                                               float* __restrict__ O2){
  const int lane = threadIdx.x & 63;
  const int wave = threadIdx.x >> 6;
  const int row  = blockIdx.y;
  const int ob   = blockIdx.x*HBLK + wave*48;   // first output col of this wave
  const int c    = ob - 8 + lane;               // load col
  const size_t rb = (size_t)row*Wh;

  float v1 = 0.f, v2 = 0.f;
  if ((unsigned)c < (unsigned)Wh){
    v1 = X1[rb + c];
    v2 = SQUARE ? v1*v1 : X2[rb + c];
  }
  // inclusive prefix sum within wave
  #pragma unroll
  for (int d=1; d<64; d<<=1){
    float t1 = __shfl_up(v1, d, 64);
    float t2 = __shfl_up(v2, d, 64);
    if (lane >= d){ v1 += t1; v2 += t2; }
  }
  float hi1 = __shfl_down(v1, 16, 64);   // P[o+16]
  float hi2 = __shfl_down(v2, 16, 64);
  float lo1 = __shfl_up(v1, 1, 64);      // P[o-1]
  float lo2 = __shfl_up(v2, 1, 64);
  if (lane == 0){ lo1 = 0.f; lo2 = 0.f; }
  int oc = ob + lane;
  if (lane < 48 && oc < Wh){
    O1[rb + oc] = hi1 - lo1;
    O2[rb + oc] = hi2 - lo2;
  }
}

// ---- FUSED: vertical 17-window of (H1,H2) -> a,b in registers -> horizontal 17-window
// of (a,b) via per-wave prefix scan -> emit Ha,Hb directly (replaces v_ab + ltm_h<false>).
// Wave strip: lane owns a,b col c = wavebase-8+lane; lanes 8..55 output their own col.
// OOB cols produce a=b=0 exactly (H loads guarded to 0 -> m=var=0), matching zero-padding.
template<int TV>
__global__ __launch_bounds__(256) void k_ltm_vh(const float* __restrict__ H1,
                                                const float* __restrict__ H2,
                                                float* __restrict__ Ha,
                                                float* __restrict__ Hb){
  const int lane = threadIdx.x & 63;
  const int wave = threadIdx.x >> 6;
  const int c    = blockIdx.x*HBLK + wave*48 - 8 + lane;  // owned a,b col
  const int i0   = blockIdx.y*TV;
  const bool cok = ((unsigned)c < (unsigned)Wh);
  const float cwf = (float)(min(c+8, Wh-1) - max(c-8, 0) + 1);

  float ws1 = 0.f, ws2 = 0.f;
  #pragma unroll
  for (int k=-8; k<=8; ++k){
    int r = i0 + k;
    if (((unsigned)r < (unsigned)Hh) && cok){
      ws1 += H1[(size_t)r*Wh + c];
      ws2 += H2[(size_t)r*Wh + c];
    }
  }
  #pragma unroll
  for (int t=0; t<TV; ++t){
    int i = i0 + t;
    float rhf = (float)(min(i+8, Hh-1) - max(i-8, 0) + 1);
    float inv = 1.0f/(rhf*cwf);
    float m   = ws1*inv;
    float var = fmaf(-m, m, ws2*inv);
    float a   = var/(var + 1e-3f);
    float b   = m*(1.0f - a);
    // horizontal 17-window over a,b via wave prefix scan
    float pa = a, pb = b;
    #pragma unroll
    for (int d=1; d<64; d<<=1){
      float ta = __shfl_up(pa, d, 64);
      float tb = __shfl_up(pb, d, 64);
      if (lane >= d){ pa += ta; pb += tb; }
    }
    float hia = __shfl_down(pa, 8, 64);   // prefix at lane+8 (col c+8)
    float hib = __shfl_down(pb, 8, 64);
    float loa = __shfl_up(pa, 9, 64);     // prefix at lane-9 (col c-9)
    float lob = __shfl_up(pb, 9, 64);
    if (lane < 9){ loa = 0.f; lob = 0.f; }
    if (lane >= 8 && lane < 56 && cok){
      Ha[(size_t)i*Wh + c] = hia - loa;
      Hb[(size_t)i*Wh + c] = hib - lob;
    }
    if (t < TV-1){
      int rn = i+9, ro = i-8;
      float n1=0.f, n2=0.f, o1=0.f, o2=0.f;
      if (cok){
        if (rn < Hh){ n1 = H1[(size_t)rn*Wh + c]; n2 = H2[(size_t)rn*Wh + c]; }
        if (ro >= 0){ o1 = H1[(size_t)ro*Wh + c]; o2 = H2[(size_t)ro*Wh + c]; }
      }
      ws1 += n1 - o1; ws2 += n2 - o2;
    }
  }
}

// Vertical 17-tap window of (Ha,Hb) = horizontal sums of (a,b); finalize bs = meanA*Ys + meanB.
template<int TV>
__global__ __launch_bounds__(256) void k_ltm_v_fin(const float* __restrict__ Ha,
                                                   const float* __restrict__ Hb,
                                                   const float* __restrict__ Ysrc,
                                                   float* __restrict__ bs){
  const int j  = blockIdx.x*256 + threadIdx.x;
  const int i0 = blockIdx.y*TV;
  const float cwf = (float)(min(j+8, Wh-1) - max(j-8, 0) + 1);
  float wa = 0.f, wb = 0.f;
  #pragma unroll
  for (int k=-8; k<=8; ++k){
    int r = i0 + k;
    if ((unsigned)r < (unsigned)Hh){
      wa += Ha[(size_t)r*Wh + j];
      wb += Hb[(size_t)r*Wh + j];
    }
  }
  #pragma unroll
  for (int t=0; t<TV; ++t){
    int i = i0 + t;
    float rhf = (float)(min(i+8, Hh-1) - max(i-8, 0) + 1);
    float inv = 1.0f/(rhf*cwf);
    bs[(size_t)i*Wh + j] = fmaf(wa*inv, Ysrc[(size_t)i*Wh + j], wb*inv);
    if (t < TV-1){
      int rn = i+9, ro = i-8;
      float na=0.f, nb=0.f, oa=0.f, ob_=0.f;
      if (rn < Hh){ na = Ha[(size_t)rn*Wh + j]; nb = Hb[(size_t)rn*Wh + j]; }
      if (ro >= 0){ oa = Ha[(size_t)ro*Wh + j]; ob_ = Hb[(size_t)ro*Wh + j]; }
      wa += na - oa; wb += nb - ob_;
    }
  }
}

// ---- AWB gains from sums (wave-uniform; inlined into consumers) ----
__device__ __forceinline__ void awb_gains(const float* __restrict__ sums, float& gr, float& gb){
  const float invS = 1.0f/(float)S;
  float rm = sums[0]*invS, g1 = sums[1]*invS, g2 = sums[2]*invS, bm = sums[3]*invS;
  float gm = 0.5f*(g1+g2);
  gr = fminf(gm/(rm + 1e-8f), 4.0f);
  gb = fminf(gm/(bm + 1e-8f), 4.0f);
}

// ---- gather 4x6 mosaic window for output cols (i,j),(i,j+1), j even ----
// mosaic rows 2i-1..2i+2, cols 2j-1..2j+4. Zero-pad outside (conv 'SAME').
__device__ __forceinline__ void load_mosaic2(const float* __restrict__ D, float gr, float gb,
                                             int i, int j, float m[4][6]){
  const float* __restrict__ P0 = D;
  const float* __restrict__ P1 = D + (size_t)S;
  const float* __restrict__ P2 = D + (size_t)2*S;
  const float* __restrict__ P3 = D + (size_t)3*S;
  const bool up = (i > 0), dn = (i < Hh-1), lf = (j > 0), rt = (j+2 < Wh);
  const size_t rc = (size_t)i*Wh + j;
  const size_t ru = rc - Wh, rd = rc + Wh;
  const float2 z = make_float2(0.f, 0.f);
  // row0: y=2i-1 (odd y): P2 even-x / P3 odd-x, plane row i-1
  {
    float2 t3 = up ? *(const float2*)(P3+ru) : z;
    float2 t2 = up ? *(const float2*)(P2+ru) : z;
    m[0][0] = (up&&lf) ? clamp01(P3[ru-1]*gb) : 0.f;
    m[0][1] = clamp01(t2.x);
    m[0][2] = clamp01(t3.x*gb);
    m[0][3] = clamp01(t2.y);
    m[0][4] = clamp01(t3.y*gb);
    m[0][5] = (up&&rt) ? clamp01(P2[ru+2]) : 0.f;
  }
  // row1: y=2i (even y): P0 even-x (gr) / P1 odd-x, plane row i
  {
    float2 t1 = *(const float2*)(P1+rc);
    float2 t0 = *(const float2*)(P0+rc);
    m[1][0] = lf ? clamp01(P1[rc-1]) : 0.f;
    m[1][1] = clamp01(t0.x*gr);
    m[1][2] = clamp01(t1.x);
    m[1][3] = clamp01(t0.y*gr);
    m[1][4] = clamp01(t1.y);
    m[1][5] = rt ? clamp01(P0[rc+2]*gr) : 0.f;
  }
  // row2: y=2i+1 (odd y): P2/P3, plane row i
  {
    float2 s3 = *(const float2*)(P3+rc);
    float2 s2 = *(const float2*)(P2+rc);
    m[2][0] = lf ? clamp01(P3[rc-1]*gb) : 0.f;
    m[2][1] = clamp01(s2.x);
    m[2][2] = clamp01(s3.x*gb);
    m[2][3] = clamp01(s2.y);
    m[2][4] = clamp01(s3.y*gb);
    m[2][5] = rt ? clamp01(P2[rc+2]) : 0.f;
  }
  // row3: y=2i+2 (even y): P0/P1, plane row i+1
  {
    float2 u1 = dn ? *(const float2*)(P1+rd) : z;
    float2 u0 = dn ? *(const float2*)(P0+rd) : z;
    m[3][0] = (dn&&lf) ? clamp01(P1[rd-1]) : 0.f;
    m[3][1] = clamp01(u0.x*gr);
    m[3][2] = clamp01(u1.x);
    m[3][3] = clamp01(u0.y*gr);
    m[3][4] = clamp01(u1.y);
    m[3][5] = (dn&&rt) ? clamp01(P0[rd+2]*gr) : 0.f;
  }
}

// demosaic+CCM on a 4x4 slice of the 4x6 window, offset o*2 (o=0,1)
template<int O>
__device__ __forceinline__ void demosaic_ccm_s(const float m[4][6], const float* __restrict__ C,
                                               float R[2][2], float G[2][2], float Bv[2][2]){
  #define MM(a,b) m[a][(b)+2*O]
  float r[2][2], g[2][2], b[2][2];
  r[0][0] = MM(1,1);
  g[0][0] = 0.25f*(MM(0,1)+MM(2,1)+MM(1,0)+MM(1,2));
  b[0][0] = 0.25f*(MM(0,0)+MM(0,2)+MM(2,0)+MM(2,2));
  r[0][1] = 0.5f*(MM(1,1)+MM(1,3));
  g[0][1] = MM(1,2);
  b[0][1] = 0.5f*(MM(0,2)+MM(2,2));
  r[1][0] = 0.5f*(MM(1,1)+MM(3,1));
  g[1][0] = MM(2,1);
  b[1][0] = 0.5f*(MM(2,0)+MM(2,2));
  r[1][1] = 0.25f*(MM(1,1)+MM(1,3)+MM(3,1)+MM(3,3));
  g[1][1] = 0.25f*(MM(1,2)+MM(3,2)+MM(2,1)+MM(2,3));
  b[1][1] = MM(2,2);
  #undef MM
  #pragma unroll
  for (int a=0; a<2; ++a){
    #pragma unroll
    for (int c=0; c<2; ++c){
      R[a][c]  = clamp01(fmaf(C[2], b[a][c], fmaf(C[1], g[a][c], C[0]*r[a][c])));
      G[a][c]  = clamp01(fmaf(C[5], b[a][c], fmaf(C[4], g[a][c], C[3]*r[a][c])));
      Bv[a][c] = clamp01(fmaf(C[8], b[a][c], fmaf(C[7], g[a][c], C[6]*r[a][c])));
    }
  }
}

// ---- half-res luma Ys (2 cols/thread) ----
__global__ __launch_bounds__(256) void k_ys(const float* __restrict__ D, const float* __restrict__ sums,
                                            const float* __restrict__ C, float* __restrict__ Ys){
  int idx = blockIdx.x*256 + threadIdx.x;
  int i = idx >> 10, j = (idx & 1023)*2;
  float gr, gb; awb_gains(sums, gr, gb);
  float m[4][6]; load_mosaic2(D, gr, gb, i, j, m);
  float y0 = 0.f, y1 = 0.f;
  {
    float R[2][2], G[2][2], Bv[2][2];
    demosaic_ccm_s<0>(m, C, R, G, Bv);
    #pragma unroll
    for (int a=0; a<2; ++a)
      #pragma unroll
      for (int c=0; c<2; ++c)
        y0 += 0.299f*R[a][c] + 0.587f*G[a][c] + 0.114f*Bv[a][c];
  }
  {
    float R[2][2], G[2][2], Bv[2][2];
    demosaic_ccm_s<1>(m, C, R, G, Bv);
    #pragma unroll
    for (int a=0; a<2; ++a)
      #pragma unroll
      for (int c=0; c<2; ++c)
        y1 += 0.299f*R[a][c] + 0.587f*G[a][c] + 0.114f*Bv[a][c];
  }
  *(float2*)(Ys + (size_t)i*Wh + j) = make_float2(0.25f*y0, 0.25f*y1);
}

// ---- final: demosaic+CCM + LTM + gamma + RGB->YUV -> NV12 (2 cols/thread) ----
__global__ __launch_bounds__(256) void k_final(const float* __restrict__ D, const float* __restrict__ sums,
                                               const float* __restrict__ C,
                                               const float* __restrict__ bs, float* __restrict__ out){
  int idx = blockIdx.x*256 + threadIdx.x;
  int i = idx >> 10, j = (idx & 1023)*2;
  float gr, gb; awb_gains(sums, gr, gb);
  float m[4][6]; load_mosaic2(D, gr, gb, i, j, m);

  // bs neighborhood rows i-1..i+1, cols j-1..j+2 (clamped)
  float bsv[3][4];
  #pragma unroll
  for (int a=0; a<3; ++a){
    int r = min(max(i-1+a, 0), Hh-1);
    const float* br = bs + ((size_t)r<<11);
    bsv[a][0] = br[max(j-1, 0)];
    float2 t = *(const float2*)(br + j);
    bsv[a][1] = t.x; bsv[a][2] = t.y;
    bsv[a][3] = br[min(j+2, Wh-1)];
  }

  float Yrow0[4], Yrow1[4], UV[4];
  #pragma unroll
  for (int o=0; o<2; ++o){
    float R[2][2], G[2][2], Bv[2][2];
    if (o==0) demosaic_ccm_s<0>(m, C, R, G, Bv);
    else      demosaic_ccm_s<1>(m, C, R, G, Bv);
    // bilinear upsample of base_s around col j+o (bsv local cols o..o+2)
    float base[2][2];
    base[0][0] = 0.0625f*bsv[0][0+o] + 0.1875f*bsv[0][1+o] + 0.1875f*bsv[1][0+o] + 0.5625f*bsv[1][1+o];
    base[0][1] = 0.1875f*bsv[0][1+o] + 0.0625f*bsv[0][2+o] + 0.5625f*bsv[1][1+o] + 0.1875f*bsv[1][2+o];
    base[1][0] = 0.1875f*bsv[1][0+o] + 0.5625f*bsv[1][1+o] + 0.0625f*bsv[2][0+o] + 0.1875f*bsv[2][1+o];
    base[1][1] = 0.5625f*bsv[1][1+o] + 0.1875f*bsv[1][2+o] + 0.1875f*bsv[2][1+o] + 0.0625f*bsv[2][2+o];

    float Uacc = 0.f, Vacc = 0.f;
    #pragma unroll
    for (int a=0; a<2; ++a){
      #pragma unroll
      for (int c=0; c<2; ++c){
        float Yl   = 0.299f*R[a][c] + 0.587f*G[a][c] + 0.114f*Bv[a][c];
        float Ynew = fmaf(0.7f, base[a][c], Yl - base[a][c]);
        float sc   = Ynew/(Yl + 1e-6f);
        float Rg = gamma22(fmaxf(clamp01(R[a][c]*sc),  1e-6f));
        float Gg = gamma22(fmaxf(clamp01(G[a][c]*sc),  1e-6f));
        float Bg = gamma22(fmaxf(clamp01(Bv[a][c]*sc), 1e-6f));
        float Yf = 0.299f*Rg + 0.587f*Gg + 0.114f*Bg;
        float Yq = fminf(fmaxf(Yf*255.0f, 0.0f), 255.0f);
        if (a==0) Yrow0[2*o+c] = Yq; else Yrow1[2*o+c] = Yq;
        Uacc += -0.168736f*Rg - 0.331264f*Gg + 0.5f*Bg + 0.5f;
        Vacc +=  0.5f*Rg - 0.418688f*Gg - 0.081312f*Bg + 0.5f;
      }
    }
    UV[2*o]   = fminf(fmaxf(0.25f*Uacc*255.0f, 0.0f), 255.0f);
    UV[2*o+1] = fminf(fmaxf(0.25f*Vacc*255.0f, 0.0f), 255.0f);
  }
  *(float4*)(out + (size_t)(2*i)*IMG_W   + 2*j) = make_float4(Yrow0[0], Yrow0[1], Yrow0[2], Yrow0[3]);
  *(float4*)(out + (size_t)(2*i+1)*IMG_W + 2*j) = make_float4(Yrow1[0], Yrow1[1], Yrow1[2], Yrow1[3]);
  *(float4*)(out + (size_t)IMG_H*IMG_W + (size_t)i*IMG_W + 2*j) = make_float4(UV[0], UV[1], UV[2], UV[3]);
}

extern "C" void kernel_launch(void* const* d_in, const int* in_sizes, int n_in,
                              void* d_out, int out_size, void* d_ws, size_t ws_size,
                              hipStream_t stream){
  const float* x   = (const float*)d_in[0];
  const float* ccm = (const float*)d_in[1];
  float* ws  = (float*)d_ws;
  float* out = (float*)d_out;

  // workspace layout (floats), total 10*S + 8:
  //  [0,4S)   P (planes); free after k_denoise ->
  //           LTM scratch: Hs1=[0,S), Hs2=[S,2S), Ha=[2S,3S), Hb=[3S,4S), bs=[0,S) (after vh)
  //  [4S,8S)  D (denoised planes) — live until k_final
  //  [8S,9S)  Ys
  //  [9S,10S) unused (kept for identical ws requirement)
  //  [10S,+8) sums[4]
  size_t need = ((size_t)10*S + 8)*sizeof(float);
  if (ws_size < need) return;

  float* P   = ws;
  float* D   = ws + (size_t)4*S;
  float* Ys  = ws + (size_t)8*S;
  float* Hs1 = ws;                      // aliases P (dead after denoise)
  float* Hs2 = ws + (size_t)S;
  float* Ha  = ws + (size_t)2*S;
  float* Hb  = ws + (size_t)3*S;
  float* bs  = ws;                      // aliases Hs1 (dead after vh)
  float* sums = ws + (size_t)10*S;

  const int nb2 = S/512;                    // 2-col kernels
  dim3 gdn(Wh/512, Hh/TID, 4);              // fused denoise, all planes, 2-col
  dim3 gh((Wh + HBLK - 1)/HBLK, Hh);        // LTM horizontal prefix kernel (11 x 1536)
  dim3 gvh((Wh + HBLK - 1)/HBLK, Hh/TVL);   // fused vertical+horizontal (11 x 192)
  dim3 gv(Wh/256, Hh/TVL);                  // LTM vertical sliding kernel (8 x 192)

  k_split<<<nb2, 256, 0, stream>>>(x, P, sums);
  k_denoise<TID><<<gdn, 256, 0, stream>>>(P, D, sums);
  k_ys<<<nb2, 256, 0, stream>>>(D, sums, ccm, Ys);
  k_ltm_h<true ><<<gh, 256, 0, stream>>>(Ys, Ys, Hs1, Hs2);
  k_ltm_vh<TVL><<<gvh, 256, 0, stream>>>(Hs1, Hs2, Ha, Hb);
  k_ltm_v_fin<TVL><<<gv, 256, 0, stream>>>(Ha, Hb, Ys, bs);
  k_final<<<nb2, 256, 0, stream>>>(D, sums, ccm, bs, out);
}

// Round 7
// 267.796 us; speedup vs baseline: 1.0576x; 1.0576x over previous
//
#include <hip/hip_runtime.h>
#include <math.h>

#define IMG_H 3072
#define IMG_W 4096
#define Hh 1536
#define Wh 2048
#define S (Hh*Wh)   // 3,145,728 per-plane pixels

#define TID 32   // rows/thread, fused denoise (trip = TID+8 = 40, unroll 5 = ring period)
#define TVL 16   // rows/thread, LTM vertical sliding pass (16 best: r5 vs r6 A/B)
#define HBLK 192 // output cols per block in LTM fused vh pass (4 waves x 48)
#define YSW 110  // output cols per wave in fused ys+h kernel (lanes 5..59, 2 cols each)

#if __has_builtin(__builtin_amdgcn_rcpf)
#define RCP(x) __builtin_amdgcn_rcpf(x)
#else
#define RCP(x) (1.0f/(x))
#endif

__device__ __forceinline__ float clamp01(float v){ return fminf(fmaxf(v, 0.0f), 1.0f); }

// jnp.interp over knots (0,0),(0.25,0.5),(1,1) then black-level
__device__ __forceinline__ float decompand_black(float v){
  float y = (v <= 0.25f) ? (2.0f*v) : fmaf(v - 0.25f, 0.5f/0.75f, 0.5f);
  y = clamp01(y);
  return clamp01((y - 0.0625f) * (1.0f/0.9375f));
}

// x^(1/2.2): v_log_f32 + v_exp_f32 (__builtin_amdgcn_logf IS log2)
__device__ __forceinline__ float gamma22(float x){
  return __builtin_amdgcn_exp2f(0.45454545454545453f * __builtin_amdgcn_logf(x));
}

// ---- K1: decompand + split into 4 RGGB planes (2 quarter-cols/thread) + zero sums ----
__global__ __launch_bounds__(256) void k_split(const float* __restrict__ x, float* __restrict__ P,
                                               float* __restrict__ sums){
  int idx = blockIdx.x*256 + threadIdx.x;
  int i = idx >> 10, jq = (idx & 1023)*2;
  const float* r0 = x + (size_t)(2*i)*IMG_W + 2*jq;
  float4 a = *(const float4*)r0;
  float4 b = *(const float4*)(r0 + IMG_W);
  size_t o = (size_t)i*Wh + jq;
  *(float2*)(P + o)            = make_float2(decompand_black(a.x), decompand_black(a.z));
  *(float2*)(P + S + o)        = make_float2(decompand_black(a.y), decompand_black(a.w));
  *(float2*)(P + 2*(size_t)S + o) = make_float2(decompand_black(b.x), decompand_black(b.z));
  *(float2*)(P + 3*(size_t)S + o) = make_float2(decompand_black(b.y), decompand_black(b.w));
  if (blockIdx.x == 0 && threadIdx.x < 4) sums[threadIdx.x] = 0.f;
}

// ---- fused guided-filter denoise (r=2, eps=100), 2 output columns/thread ----
// a-cols k=0..5 <-> col c0-2+k ; I-cols c0-4..c0+5 (10). FAST: interior, count=25.
template<int TI, bool FAST>
__device__ __forceinline__ void denoise_col2(const float* __restrict__ in, float* __restrict__ D,
                                             int c0, int i0, float& local){
  const float inv25 = 1.0f/25.0f;
  float cw_a[6], amask[6], cw_o0 = 25.f, cw_o1 = 25.f;
  if (!FAST){
    #pragma unroll
    for (int k=0;k<6;++k){
      int pc = c0 + k - 2;
      bool ok = ((unsigned)pc < (unsigned)Wh);
      amask[k] = ok ? 1.f : 0.f;
      cw_a[k]  = ok ? (float)(min(pc+2, Wh-1) - max(pc-2, 0) + 1) : 1.f;
    }
    cw_o0 = (float)(min(c0+2, Wh-1)   - max(c0-2, 0) + 1);
    cw_o1 = (float)(min(c0+3, Wh-1)   - max(c0-1, 0) + 1);
  }

  float rh1[6][5]={{0}}, rh2[6][5]={{0}};
  float vs1[6]={0}, vs2[6]={0};
  float rha0[5]={0}, rhb0[5]={0}, rha1[5]={0}, rhb1[5]={0};
  float cI0[5]={0}, cI1[5]={0};
  float wa0=0.f, wb0=0.f, wa1=0.f, wb1=0.f;

  const float* rp = in + (size_t)(i0-4)*Wh + c0;   // loads rp[-4..5]
  float* wp = D + (size_t)i0*Wh + c0;

  #pragma unroll 5
  for (int rr=0; rr<TI+8; ++rr){
    int r = i0 - 4 + rr;
    float v[10];
    if (FAST){
      float2 p0 = *(const float2*)(rp-4);
      float2 p1 = *(const float2*)(rp-2);
      float2 p2 = *(const float2*)(rp);
      float2 p3 = *(const float2*)(rp+2);
      float2 p4 = *(const float2*)(rp+4);
      v[0]=p0.x; v[1]=p0.y; v[2]=p1.x; v[3]=p1.y; v[4]=p2.x;
      v[5]=p2.y; v[6]=p3.x; v[7]=p3.y; v[8]=p4.x; v[9]=p4.y;
    } else {
      if ((unsigned)r < (unsigned)Hh){
        #pragma unroll
        for (int d=0; d<10; ++d){
          int c = c0 + d - 4;
          v[d] = ((unsigned)c < (unsigned)Wh) ? rp[d-4] : 0.f;
        }
      } else {
        #pragma unroll
        for (int d=0; d<10; ++d) v[d]=0.f;
      }
    }
    rp += Wh;
    float sq[10];
    #pragma unroll
    for (int d=0; d<10; ++d) sq[d]=v[d]*v[d];
    float h1[6], h2[6];
    h1[0]=v[0]+v[1]+v[2]+v[3]+v[4];
    h2[0]=sq[0]+sq[1]+sq[2]+sq[3]+sq[4];
    #pragma unroll
    for (int k=1;k<6;++k){
      h1[k]=h1[k-1]-v[k-1]+v[k+4];
      h2[k]=h2[k-1]-sq[k-1]+sq[k+4];
    }
    #pragma unroll
    for (int k=0;k<6;++k){
      vs1[k]+=h1[k]-rh1[k][0];
      vs2[k]+=h2[k]-rh2[k][0];
      #pragma unroll
      for (int t=0;t<4;++t){ rh1[k][t]=rh1[k][t+1]; rh2[k][t]=rh2[k][t+1]; }
      rh1[k][4]=h1[k]; rh2[k][4]=h2[k];
    }
    #pragma unroll
    for (int t=0;t<4;++t){ cI0[t]=cI0[t+1]; cI1[t]=cI1[t+1]; }
    cI0[4]=v[4]; cI1[4]=v[5];

    if (rr >= 4){
      int q = r-2;
      float a6[6], b6[6];
      if (FAST){
        #pragma unroll
        for (int k=0;k<6;++k){
          float m   = vs1[k]*inv25;
          float var = fmaf(-m, m, vs2[k]*inv25);
          float a   = var*RCP(var + 100.0f);
          a6[k] = a; b6[k] = fmaf(-m, a, m);
        }
      } else {
        float rmask = ((unsigned)q < (unsigned)Hh) ? 1.f : 0.f;
        float rh = (float)(min(q+2, Hh-1) - max(q-2, 0) + 1);
        #pragma unroll
        for (int k=0;k<6;++k){
          float inv = RCP(rh*cw_a[k]);
          float m   = vs1[k]*inv;
          float var = fmaf(-m, m, vs2[k]*inv);
          float a   = var*RCP(var + 100.0f);
          float b   = fmaf(-m, a, m);
          a6[k] = a*amask[k]*rmask; b6[k] = b*amask[k]*rmask;
        }
      }
      float ha0 = a6[0]+a6[1]+a6[2]+a6[3]+a6[4];
      float hb0 = b6[0]+b6[1]+b6[2]+b6[3]+b6[4];
      float ha1 = ha0 - a6[0] + a6[5];
      float hb1 = hb0 - b6[0] + b6[5];
      wa0 += ha0 - rha0[0]; wb0 += hb0 - rhb0[0];
      wa1 += ha1 - rha1[0]; wb1 += hb1 - rhb1[0];
      #pragma unroll
      for (int t=0;t<4;++t){
        rha0[t]=rha0[t+1]; rhb0[t]=rhb0[t+1];
        rha1[t]=rha1[t+1]; rhb1[t]=rhb1[t+1];
      }
      rha0[4]=ha0; rhb0[4]=hb0; rha1[4]=ha1; rhb1[4]=hb1;

      if (rr >= 8){
        int ro = r-4;
        float invo0, invo1;
        if (FAST){ invo0 = inv25; invo1 = inv25; }
        else {
          float rho = (float)(min(ro+2, Hh-1) - max(ro-2, 0) + 1);
          invo0 = RCP(rho*cw_o0); invo1 = RCP(rho*cw_o1);
        }
        float d0 = fmaf(wa0*invo0, cI0[0], wb0*invo0);
        float d1 = fmaf(wa1*invo1, cI1[0], wb1*invo1);
        *(float2*)wp = make_float2(d0, d1); wp += Wh;
        local += d0 + d1;
      }
    }
  }
}

template<int TI>
__global__ __launch_bounds__(256) void k_denoise(const float* __restrict__ P4,
                                                 float* __restrict__ D4,
                                                 float* __restrict__ sums){
  const int c0 = (blockIdx.x*256 + threadIdx.x)*2;
  const int i0 = blockIdx.y*TI;
  const int pl = blockIdx.z;
  const float* __restrict__ in = P4 + (size_t)pl*S;
  float* __restrict__ D = D4 + (size_t)pl*S;
  float local = 0.f;

  // wave-uniform fast check: wave covers cols [cmin, cmin+127], touches [cmin-4, cmin+131]
  const int cmin = (blockIdx.x*256 + (threadIdx.x & ~63))*2;
  const bool rows_ok = (i0 >= 4) && (i0 + TI + 4 <= Hh);
  const bool fast = rows_ok && (cmin >= 4) && (cmin + 131 < Wh);
  if (fast) denoise_col2<TI, true >(in, D, c0, i0, local);
  else      denoise_col2<TI, false>(in, D, c0, i0, local);

  __shared__ float red[256];
  red[threadIdx.x]=local;
  __syncthreads();
  #pragma unroll
  for (int off=128; off>0; off>>=1){
    if (threadIdx.x<off) red[threadIdx.x]+=red[threadIdx.x+off];
    __syncthreads();
  }
  if (threadIdx.x==0) atomicAdd(sums+pl, red[0]);
}

// ---- AWB gains from sums (wave-uniform; inlined into consumers) ----
__device__ __forceinline__ void awb_gains(const float* __restrict__ sums, float& gr, float& gb){
  const float invS = 1.0f/(float)S;
  float rm = sums[0]*invS, g1 = sums[1]*invS, g2 = sums[2]*invS, bm = sums[3]*invS;
  float gm = 0.5f*(g1+g2);
  gr = fminf(gm/(rm + 1e-8f), 4.0f);
  gb = fminf(gm/(bm + 1e-8f), 4.0f);
}

// ---- gather 4x6 mosaic window for output cols (i,j),(i,j+1), j even ----
// mosaic rows 2i-1..2i+2, cols 2j-1..2j+4. Zero-pad outside (conv 'SAME').
__device__ __forceinline__ void load_mosaic2(const float* __restrict__ D, float gr, float gb,
                                             int i, int j, float m[4][6]){
  const float* __restrict__ P0 = D;
  const float* __restrict__ P1 = D + (size_t)S;
  const float* __restrict__ P2 = D + (size_t)2*S;
  const float* __restrict__ P3 = D + (size_t)3*S;
  const bool up = (i > 0), dn = (i < Hh-1), lf = (j > 0), rt = (j+2 < Wh);
  const size_t rc = (size_t)i*Wh + j;
  const size_t ru = rc - Wh, rd = rc + Wh;
  const float2 z = make_float2(0.f, 0.f);
  // row0: y=2i-1 (odd y): P2 even-x / P3 odd-x, plane row i-1
  {
    float2 t3 = up ? *(const float2*)(P3+ru) : z;
    float2 t2 = up ? *(const float2*)(P2+ru) : z;
    m[0][0] = (up&&lf) ? clamp01(P3[ru-1]*gb) : 0.f;
    m[0][1] = clamp01(t2.x);
    m[0][2] = clamp01(t3.x*gb);
    m[0][3] = clamp01(t2.y);
    m[0][4] = clamp01(t3.y*gb);
    m[0][5] = (up&&rt) ? clamp01(P2[ru+2]) : 0.f;
  }
  // row1: y=2i (even y): P0 even-x (gr) / P1 odd-x, plane row i
  {
    float2 t1 = *(const float2*)(P1+rc);
    float2 t0 = *(const float2*)(P0+rc);
    m[1][0] = lf ? clamp01(P1[rc-1]) : 0.f;
    m[1][1] = clamp01(t0.x*gr);
    m[1][2] = clamp01(t1.x);
    m[1][3] = clamp01(t0.y*gr);
    m[1][4] = clamp01(t1.y);
    m[1][5] = rt ? clamp01(P0[rc+2]*gr) : 0.f;
  }
  // row2: y=2i+1 (odd y): P2/P3, plane row i
  {
    float2 s3 = *(const float2*)(P3+rc);
    float2 s2 = *(const float2*)(P2+rc);
    m[2][0] = lf ? clamp01(P3[rc-1]*gb) : 0.f;
    m[2][1] = clamp01(s2.x);
    m[2][2] = clamp01(s3.x*gb);
    m[2][3] = clamp01(s2.y);
    m[2][4] = clamp01(s3.y*gb);
    m[2][5] = rt ? clamp01(P2[rc+2]) : 0.f;
  }
  // row3: y=2i+2 (even y): P0/P1, plane row i+1
  {
    float2 u1 = dn ? *(const float2*)(P1+rd) : z;
    float2 u0 = dn ? *(const float2*)(P0+rd) : z;
    m[3][0] = (dn&&lf) ? clamp01(P1[rd-1]) : 0.f;
    m[3][1] = clamp01(u0.x*gr);
    m[3][2] = clamp01(u1.x);
    m[3][3] = clamp01(u0.y*gr);
    m[3][4] = clamp01(u1.y);
    m[3][5] = (dn&&rt) ? clamp01(P0[rd+2]*gr) : 0.f;
  }
}

// demosaic+CCM on a 4x4 slice of the 4x6 window, offset o*2 (o=0,1)
template<int O>
__device__ __forceinline__ void demosaic_ccm_s(const float m[4][6], const float* __restrict__ C,
                                               float R[2][2], float G[2][2], float Bv[2][2]){
  #define MM(a,b) m[a][(b)+2*O]
  float r[2][2], g[2][2], b[2][2];
  r[0][0] = MM(1,1);
  g[0][0] = 0.25f*(MM(0,1)+MM(2,1)+MM(1,0)+MM(1,2));
  b[0][0] = 0.25f*(MM(0,0)+MM(0,2)+MM(2,0)+MM(2,2));
  r[0][1] = 0.5f*(MM(1,1)+MM(1,3));
  g[0][1] = MM(1,2);
  b[0][1] = 0.5f*(MM(0,2)+MM(2,2));
  r[1][0] = 0.5f*(MM(1,1)+MM(3,1));
  g[1][0] = MM(2,1);
  b[1][0] = 0.5f*(MM(2,0)+MM(2,2));
  r[1][1] = 0.25f*(MM(1,1)+MM(1,3)+MM(3,1)+MM(3,3));
  g[1][1] = 0.25f*(MM(1,2)+MM(3,2)+MM(2,1)+MM(2,3));
  b[1][1] = MM(2,2);
  #undef MM
  #pragma unroll
  for (int a=0; a<2; ++a){
    #pragma unroll
    for (int c=0; c<2; ++c){
      R[a][c]  = clamp01(fmaf(C[2], b[a][c], fmaf(C[1], g[a][c], C[0]*r[a][c])));
      G[a][c]  = clamp01(fmaf(C[5], b[a][c], fmaf(C[4], g[a][c], C[3]*r[a][c])));
      Bv[a][c] = clamp01(fmaf(C[8], b[a][c], fmaf(C[7], g[a][c], C[6]*r[a][c])));
    }
  }
}

// ---- FUSED: half-res luma Ys + horizontal 17-tap sums (Ys, Ys^2) via pair prefix scan ----
// Wave strip: lane L owns cols gc0=base+2L, gc0+1 (base = strip*YSW - 10, even).
// Lanes 5..59 output their 2 cols (110/strip). prefixAt(even 2k)=P(k)-y1(k);
// prefixAt(odd 2k+1)=P(k). H[c] = prefixAt(c+8) - prefixAt(c-9). OOB cols give y=0
// (truncated-window semantics; normalization by true counts happens downstream).
__global__ __launch_bounds__(256) void k_ys_h(const float* __restrict__ D, const float* __restrict__ sums,
                                              const float* __restrict__ C, float* __restrict__ Ys,
                                              float* __restrict__ H1, float* __restrict__ H2){
  const int lane = threadIdx.x & 63;
  const int wave = threadIdx.x >> 6;
  const int i    = blockIdx.y;                  // half-res row
  const int strip= blockIdx.x*4 + wave;
  const int base = strip*YSW - 10;              // even
  const int gc0  = base + 2*lane;               // owned even col
  const bool cok = ((unsigned)gc0 < (unsigned)Wh);

  float gr, gb; awb_gains(sums, gr, gb);
  float y0 = 0.f, y1 = 0.f;
  if (cok){
    float m[4][6]; load_mosaic2(D, gr, gb, i, gc0, m);
    {
      float R[2][2], G[2][2], Bv[2][2];
      demosaic_ccm_s<0>(m, C, R, G, Bv);
      #pragma unroll
      for (int a=0; a<2; ++a)
        #pragma unroll
        for (int c=0; c<2; ++c)
          y0 += 0.299f*R[a][c] + 0.587f*G[a][c] + 0.114f*Bv[a][c];
    }
    {
      float R[2][2], G[2][2], Bv[2][2];
      demosaic_ccm_s<1>(m, C, R, G, Bv);
      #pragma unroll
      for (int a=0; a<2; ++a)
        #pragma unroll
        for (int c=0; c<2; ++c)
          y1 += 0.299f*R[a][c] + 0.587f*G[a][c] + 0.114f*Bv[a][c];
    }
    y0 *= 0.25f; y1 *= 0.25f;
  }
  const float q1 = y1*y1;           // odd-col square (needed for prefixAt at even cols)
  float P1 = y0 + y1;
  float P2 = y0*y0 + q1;
  #pragma unroll
  for (int d=1; d<64; d<<=1){
    float t1 = __shfl_up(P1, d, 64);
    float t2 = __shfl_up(P2, d, 64);
    if (lane >= d){ P1 += t1; P2 += t2; }
  }
  float Pd4_1 = __shfl_down(P1, 4, 64), Pd4_2 = __shfl_down(P2, 4, 64);
  float Pu5_1 = __shfl_up(P1, 5, 64),  Pu5_2 = __shfl_up(P2, 5, 64);
  float Pu4_1 = __shfl_up(P1, 4, 64),  Pu4_2 = __shfl_up(P2, 4, 64);
  float y1d4  = __shfl_down(y1, 4, 64), y1u4 = __shfl_up(y1, 4, 64);
  float q1d4  = __shfl_down(q1, 4, 64), q1u4 = __shfl_up(q1, 4, 64);

  if (lane >= 5 && lane < 60 && cok){
    size_t rb = (size_t)i*Wh + gc0;
    *(float2*)(Ys + rb) = make_float2(y0, y1);
    // even col gc0: prefixAt(2L+8)=Pd4-y1d4 ; prefixAt(2L-9)=Pu5
    float h1e = (Pd4_1 - y1d4) - Pu5_1;
    float h2e = (Pd4_2 - q1d4) - Pu5_2;
    // odd col gc0+1: prefixAt(2L+9)=Pd4 ; prefixAt(2L-8)=Pu4-y1u4
    float h1o = Pd4_1 - (Pu4_1 - y1u4);
    float h2o = Pd4_2 - (Pu4_2 - q1u4);
    *(float2*)(H1 + rb) = make_float2(h1e, h1o);
    *(float2*)(H2 + rb) = make_float2(h2e, h2o);
  }
}

// ---- FUSED: vertical 17-window of (H1,H2) -> a,b in registers -> horizontal 17-window
// of (a,b) via per-wave prefix scan -> emit Ha,Hb directly.
// Wave strip: lane owns a,b col c = wavebase-8+lane; lanes 8..55 output their own col.
// OOB cols produce a=b=0 exactly (H loads guarded to 0 -> m=var=0), matching zero-padding.
template<int TV>
__global__ __launch_bounds__(256) void k_ltm_vh(const float* __restrict__ H1,
                                                const float* __restrict__ H2,
                                                float* __restrict__ Ha,
                                                float* __restrict__ Hb){
  const int lane = threadIdx.x & 63;
  const int wave = threadIdx.x >> 6;
  const int c    = blockIdx.x*HBLK + wave*48 - 8 + lane;  // owned a,b col
  const int i0   = blockIdx.y*TV;
  const bool cok = ((unsigned)c < (unsigned)Wh);
  const float cwf = (float)(min(c+8, Wh-1) - max(c-8, 0) + 1);

  float ws1 = 0.f, ws2 = 0.f;
  #pragma unroll
  for (int k=-8; k<=8; ++k){
    int r = i0 + k;
    if (((unsigned)r < (unsigned)Hh) && cok){
      ws1 += H1[(size_t)r*Wh + c];
      ws2 += H2[(size_t)r*Wh + c];
    }
  }
  #pragma unroll
  for (int t=0; t<TV; ++t){
    int i = i0 + t;
    float rhf = (float)(min(i+8, Hh-1) - max(i-8, 0) + 1);
    float inv = 1.0f/(rhf*cwf);
    float m   = ws1*inv;
    float var = fmaf(-m, m, ws2*inv);
    float a   = var/(var + 1e-3f);
    float b   = m*(1.0f - a);
    // horizontal 17-window over a,b via wave prefix scan
    float pa = a, pb = b;
    #pragma unroll
    for (int d=1; d<64; d<<=1){
      float ta = __shfl_up(pa, d, 64);
      float tb = __shfl_up(pb, d, 64);
      if (lane >= d){ pa += ta; pb += tb; }
    }
    float hia = __shfl_down(pa, 8, 64);   // prefix at lane+8 (col c+8)
    float hib = __shfl_down(pb, 8, 64);
    float loa = __shfl_up(pa, 9, 64);     // prefix at lane-9 (col c-9)
    float lob = __shfl_up(pb, 9, 64);
    if (lane < 9){ loa = 0.f; lob = 0.f; }
    if (lane >= 8 && lane < 56 && cok){
      Ha[(size_t)i*Wh + c] = hia - loa;
      Hb[(size_t)i*Wh + c] = hib - lob;
    }
    if (t < TV-1){
      int rn = i+9, ro = i-8;
      float n1=0.f, n2=0.f, o1=0.f, o2=0.f;
      if (cok){
        if (rn < Hh){ n1 = H1[(size_t)rn*Wh + c]; n2 = H2[(size_t)rn*Wh + c]; }
        if (ro >= 0){ o1 = H1[(size_t)ro*Wh + c]; o2 = H2[(size_t)ro*Wh + c]; }
      }
      ws1 += n1 - o1; ws2 += n2 - o2;
    }
  }
}

// Vertical 17-tap window of (Ha,Hb) = horizontal sums of (a,b); finalize bs = meanA*Ys + meanB.
template<int TV>
__global__ __launch_bounds__(256) void k_ltm_v_fin(const float* __restrict__ Ha,
                                                   const float* __restrict__ Hb,
                                                   const float* __restrict__ Ysrc,
                                                   float* __restrict__ bs){
  const int j  = blockIdx.x*256 + threadIdx.x;
  const int i0 = blockIdx.y*TV;
  const float cwf = (float)(min(j+8, Wh-1) - max(j-8, 0) + 1);
  float wa = 0.f, wb = 0.f;
  #pragma unroll
  for (int k=-8; k<=8; ++k){
    int r = i0 + k;
    if ((unsigned)r < (unsigned)Hh){
      wa += Ha[(size_t)r*Wh + j];
      wb += Hb[(size_t)r*Wh + j];
    }
  }
  #pragma unroll
  for (int t=0; t<TV; ++t){
    int i = i0 + t;
    float rhf = (float)(min(i+8, Hh-1) - max(i-8, 0) + 1);
    float inv = 1.0f/(rhf*cwf);
    bs[(size_t)i*Wh + j] = fmaf(wa*inv, Ysrc[(size_t)i*Wh + j], wb*inv);
    if (t < TV-1){
      int rn = i+9, ro = i-8;
      float na=0.f, nb=0.f, oa=0.f, ob_=0.f;
      if (rn < Hh){ na = Ha[(size_t)rn*Wh + j]; nb = Hb[(size_t)rn*Wh + j]; }
      if (ro >= 0){ oa = Ha[(size_t)ro*Wh + j]; ob_ = Hb[(size_t)ro*Wh + j]; }
      wa += na - oa; wb += nb - ob_;
    }
  }
}

// ---- final: demosaic+CCM + LTM + gamma + RGB->YUV -> NV12 (2 cols/thread) ----
__global__ __launch_bounds__(256) void k_final(const float* __restrict__ D, const float* __restrict__ sums,
                                               const float* __restrict__ C,
                                               const float* __restrict__ bs, float* __restrict__ out){
  int idx = blockIdx.x*256 + threadIdx.x;
  int i = idx >> 10, j = (idx & 1023)*2;
  float gr, gb; awb_gains(sums, gr, gb);
  float m[4][6]; load_mosaic2(D, gr, gb, i, j, m);

  // bs neighborhood rows i-1..i+1, cols j-1..j+2 (clamped)
  float bsv[3][4];
  #pragma unroll
  for (int a=0; a<3; ++a){
    int r = min(max(i-1+a, 0), Hh-1);
    const float* br = bs + ((size_t)r<<11);
    bsv[a][0] = br[max(j-1, 0)];
    float2 t = *(const float2*)(br + j);
    bsv[a][1] = t.x; bsv[a][2] = t.y;
    bsv[a][3] = br[min(j+2, Wh-1)];
  }

  float Yrow0[4], Yrow1[4], UV[4];
  #pragma unroll
  for (int o=0; o<2; ++o){
    float R[2][2], G[2][2], Bv[2][2];
    if (o==0) demosaic_ccm_s<0>(m, C, R, G, Bv);
    else      demosaic_ccm_s<1>(m, C, R, G, Bv);
    // bilinear upsample of base_s around col j+o (bsv local cols o..o+2)
    float base[2][2];
    base[0][0] = 0.0625f*bsv[0][0+o] + 0.1875f*bsv[0][1+o] + 0.1875f*bsv[1][0+o] + 0.5625f*bsv[1][1+o];
    base[0][1] = 0.1875f*bsv[0][1+o] + 0.0625f*bsv[0][2+o] + 0.5625f*bsv[1][1+o] + 0.1875f*bsv[1][2+o];
    base[1][0] = 0.1875f*bsv[1][0+o] + 0.5625f*bsv[1][1+o] + 0.0625f*bsv[2][0+o] + 0.1875f*bsv[2][1+o];
    base[1][1] = 0.5625f*bsv[1][1+o] + 0.1875f*bsv[1][2+o] + 0.1875f*bsv[2][1+o] + 0.0625f*bsv[2][2+o];

    float Uacc = 0.f, Vacc = 0.f;
    #pragma unroll
    for (int a=0; a<2; ++a){
      #pragma unroll
      for (int c=0; c<2; ++c){
        float Yl   = 0.299f*R[a][c] + 0.587f*G[a][c] + 0.114f*Bv[a][c];
        float Ynew = fmaf(0.7f, base[a][c], Yl - base[a][c]);
        float sc   = Ynew/(Yl + 1e-6f);
        float Rg = gamma22(fmaxf(clamp01(R[a][c]*sc),  1e-6f));
        float Gg = gamma22(fmaxf(clamp01(G[a][c]*sc),  1e-6f));
        float Bg = gamma22(fmaxf(clamp01(Bv[a][c]*sc), 1e-6f));
        float Yf = 0.299f*Rg + 0.587f*Gg + 0.114f*Bg;
        float Yq = fminf(fmaxf(Yf*255.0f, 0.0f), 255.0f);
        if (a==0) Yrow0[2*o+c] = Yq; else Yrow1[2*o+c] = Yq;
        Uacc += -0.168736f*Rg - 0.331264f*Gg + 0.5f*Bg + 0.5f;
        Vacc +=  0.5f*Rg - 0.418688f*Gg - 0.081312f*Bg + 0.5f;
      }
    }
    UV[2*o]   = fminf(fmaxf(0.25f*Uacc*255.0f, 0.0f), 255.0f);
    UV[2*o+1] = fminf(fmaxf(0.25f*Vacc*255.0f, 0.0f), 255.0f);
  }
  *(float4*)(out + (size_t)(2*i)*IMG_W   + 2*j) = make_float4(Yrow0[0], Yrow0[1], Yrow0[2], Yrow0[3]);
  *(float4*)(out + (size_t)(2*i+1)*IMG_W + 2*j) = make_float4(Yrow1[0], Yrow1[1], Yrow1[2], Yrow1[3]);
  *(float4*)(out + (size_t)IMG_H*IMG_W + (size_t)i*IMG_W + 2*j) = make_float4(UV[0], UV[1], UV[2], UV[3]);
}

extern "C" void kernel_launch(void* const* d_in, const int* in_sizes, int n_in,
                              void* d_out, int out_size, void* d_ws, size_t ws_size,
                              hipStream_t stream){
  const float* x   = (const float*)d_in[0];
  const float* ccm = (const float*)d_in[1];
  float* ws  = (float*)d_ws;
  float* out = (float*)d_out;

  // workspace layout (floats), total 10*S + 8:
  //  [0,4S)   P (planes); free after k_denoise ->
  //           LTM scratch: Hs1=[0,S), Hs2=[S,2S), Ha=[2S,3S), Hb=[3S,4S), bs=[0,S) (after vh)
  //  [4S,8S)  D (denoised planes) — live until k_final
  //  [8S,9S)  Ys
  //  [9S,10S) unused (kept for identical ws requirement)
  //  [10S,+8) sums[4]
  size_t need = ((size_t)10*S + 8)*sizeof(float);
  if (ws_size < need) return;

  float* P   = ws;
  float* D   = ws + (size_t)4*S;
  float* Ys  = ws + (size_t)8*S;
  float* Hs1 = ws;                      // aliases P (dead after denoise)
  float* Hs2 = ws + (size_t)S;
  float* Ha  = ws + (size_t)2*S;
  float* Hb  = ws + (size_t)3*S;
  float* bs  = ws;                      // aliases Hs1 (dead after vh)
  float* sums = ws + (size_t)10*S;

  const int nb2 = S/512;                    // 2-col kernels
  dim3 gdn(Wh/512, Hh/TID, 4);              // fused denoise, all planes, 2-col
  dim3 gysh((Wh + 4*YSW - 1)/(4*YSW), Hh);  // fused Ys + horizontal (5 x 1536)
  dim3 gvh((Wh + HBLK - 1)/HBLK, Hh/TVL);   // fused vertical+horizontal (11 x 96)
  dim3 gv(Wh/256, Hh/TVL);                  // LTM vertical sliding kernel (8 x 96)

  k_split<<<nb2, 256, 0, stream>>>(x, P, sums);
  k_denoise<TID><<<gdn, 256, 0, stream>>>(P, D, sums);
  k_ys_h<<<gysh, 256, 0, stream>>>(D, sums, ccm, Ys, Hs1, Hs2);
  k_ltm_vh<TVL><<<gvh, 256, 0, stream>>>(Hs1, Hs2, Ha, Hb);
  k_ltm_v_fin<TVL><<<gv, 256, 0, stream>>>(Ha, Hb, Ys, bs);
  k_final<<<nb2, 256, 0, stream>>>(D, sums, ccm, bs, out);
}